// Round 1
// baseline (1674.462 us; speedup 1.0000x reference)
//
#include <hip/hip_runtime.h>
#include <stdint.h>

#define NN 50000
#define EE 640000
#define DD 128
#define LL 5
#define GG 128
#define D2 256

using bf16x8 = __attribute__((ext_vector_type(8))) short;
using f32x4v = __attribute__((ext_vector_type(4))) float;
using u32x4v = __attribute__((ext_vector_type(4))) unsigned int;

__device__ __forceinline__ unsigned short f2bf(float f){
  union { float f; uint32_t u; } c; c.f = f;
  uint32_t u = c.u;
  uint32_t r = (u + 0x7FFFu + ((u >> 16) & 1u)) >> 16;
  return (unsigned short)r;
}

// ---------------- setup kernels ----------------

__global__ __launch_bounds__(256) void zero_kernel(float* p, int n){
  int i = blockIdx.x*256 + threadIdx.x;
  if (i < n) p[i] = 0.f;
}

__global__ __launch_bounds__(256) void count_kernel(const int* __restrict__ ei, int* __restrict__ counts){
  int e = blockIdx.x*256 + threadIdx.x;
  if (e < EE) atomicAdd(&counts[ei[EE + e]], 1);
}

#define SCAN_B 512
__global__ __launch_bounds__(SCAN_B) void scan1_kernel(const int* __restrict__ counts, int* __restrict__ bsums, int n){
  __shared__ int sh[SCAN_B];
  int b = blockIdx.x, t = threadIdx.x;
  int i = b*SCAN_B + t;
  sh[t] = (i < n) ? counts[i] : 0;
  __syncthreads();
  for (int s = SCAN_B/2; s > 0; s >>= 1){
    if (t < s) sh[t] += sh[t+s];
    __syncthreads();
  }
  if (t == 0) bsums[b] = sh[0];
}

__global__ void scan2_kernel(int* bsums, int nb){
  if (threadIdx.x == 0){
    int run = 0;
    for (int i = 0; i < nb; ++i){ int v = bsums[i]; bsums[i] = run; run += v; }
  }
}

__global__ __launch_bounds__(SCAN_B) void scan3_kernel(const int* __restrict__ counts, const int* __restrict__ bsums,
                                                       int* __restrict__ startp, int* __restrict__ cursor, int n){
  __shared__ int sh[SCAN_B];
  int b = blockIdx.x, t = threadIdx.x;
  int i = b*SCAN_B + t;
  int v = (i < n) ? counts[i] : 0;
  sh[t] = v;
  __syncthreads();
  for (int s = 1; s < SCAN_B; s <<= 1){
    int add = (t >= s) ? sh[t-s] : 0;
    __syncthreads();
    sh[t] += add;
    __syncthreads();
  }
  int excl = sh[t] - v + bsums[b];
  if (i < n){ startp[i] = excl; cursor[i] = excl; }
  if (i == n-1) startp[n] = excl + v;
}

__global__ __launch_bounds__(256) void fill_kernel(const int* __restrict__ ei, int* __restrict__ cursor, int* __restrict__ csr){
  int e = blockIdx.x*256 + threadIdx.x;
  if (e < EE){
    int d = ei[EE + e];
    int slot = atomicAdd(&cursor[d], 1);
    csr[slot] = e;
  }
}

__global__ void gstart_kernel(const int* __restrict__ batch, int* __restrict__ gstart){
  int g = threadIdx.x;
  if (g > GG) return;
  int lo = 0, hi = NN;
  while (lo < hi){ int mid = (lo+hi) >> 1; if (batch[mid] < g) lo = mid+1; else hi = mid; }
  gstart[g] = lo;
}

__global__ __launch_bounds__(256) void embed_kernel(const int* __restrict__ x, const float* __restrict__ emb, float* __restrict__ h){
  int idx = blockIdx.x*256 + threadIdx.x;
  if (idx >= NN*32) return;
  int i = idx >> 5, c4 = idx & 31;
  int xi = x[i];
  *(f32x4v*)(h + (size_t)idx*4) = *(const f32x4v*)(emb + ((size_t)xi*32 + c4)*4);
}

__global__ __launch_bounds__(256) void vninit_kernel(const float* __restrict__ vn_emb, float* __restrict__ vn){
  int idx = blockIdx.x*256 + threadIdx.x;
  if (idx >= GG*32) return;
  *(f32x4v*)(vn + (size_t)idx*4) = *(const f32x4v*)(vn_emb + (size_t)(idx & 31)*4);
}

__global__ __launch_bounds__(256) void wtrans_kernel(const float* __restrict__ W1, const float* __restrict__ W2,
                                                     unsigned short* __restrict__ W1T, unsigned short* __restrict__ W2T){
  int idx = blockIdx.x*256 + threadIdx.x;
  const int total = LL*DD*D2;
  if (idx < total){
    int l = idx / (DD*D2);
    int rem = idx - l*(DD*D2);
    int k = rem / D2;          // 0..127 input dim
    int c = rem - k*D2;        // 0..255 output col
    W1T[(size_t)l*32768 + (size_t)c*128 + k] = f2bf(W1[idx]);
  } else if (idx < 2*total){
    int j = idx - total;
    int l = j / (DD*D2);
    int rem = j - l*(DD*D2);
    int k = rem / DD;          // 0..255 input dim
    int c = rem - k*DD;        // 0..127 output col
    W2T[(size_t)l*32768 + (size_t)c*256 + k] = f2bf(W2[j]);
  }
}

// ---------------- per-layer kernels ----------------

__global__ __launch_bounds__(256) void hin_kernel(const float* __restrict__ h, const float* __restrict__ vn,
                                                  const int* __restrict__ batch, float* __restrict__ hin){
  int idx = blockIdx.x*256 + threadIdx.x;
  if (idx >= NN*32) return;
  int i = idx >> 5, c4 = idx & 31;
  int b = batch[i];
  f32x4v hv = *(const f32x4v*)(h + (size_t)idx*4);
  f32x4v vv = *(const f32x4v*)(vn + ((size_t)b*32 + c4)*4);
  *(f32x4v*)(hin + (size_t)idx*4) = hv + vv;
}

// block per dst node; thread d owns feature d. Computes z = (1+eps)*hin + sum_e relu(hin[src]+edgeMLP) -> bf16
__global__ __launch_bounds__(128) void agg_kernel(const float* __restrict__ hin, const int* __restrict__ csr,
                                                  const int* __restrict__ startp, const int* __restrict__ ei,
                                                  const float* __restrict__ ea, const float* __restrict__ eW,
                                                  const float* __restrict__ eb, const float* __restrict__ eps, int l,
                                                  unsigned short* __restrict__ zout){
  int node = blockIdx.x, d = threadIdx.x;
  int s0 = startp[node], s1 = startp[node+1];
  float w[7];
  #pragma unroll
  for (int k = 0; k < 7; ++k) w[k] = eW[k*128 + d];
  float bd = eb[d];
  float acc = 0.f;
  __shared__ int eids[32];
  __shared__ int srcs[32];
  __shared__ float eav[32][8];
  for (int base = s0; base < s1; base += 32){
    int cnt = min(32, s1 - base);
    __syncthreads();
    if (d < cnt){ int e = csr[base + d]; eids[d] = e; srcs[d] = ei[e]; }
    __syncthreads();
    for (int q = d; q < cnt*7; q += 128){
      int j = q / 7, k = q - j*7;
      eav[j][k] = ea[(size_t)eids[j]*7 + k];
    }
    __syncthreads();
    for (int j = 0; j < cnt; ++j){
      float hv = hin[(size_t)srcs[j]*128 + d];
      float e = bd;
      #pragma unroll
      for (int k = 0; k < 7; ++k) e += eav[j][k]*w[k];
      float m = hv + e;
      acc += (m > 0.f) ? m : 0.f;
    }
  }
  float one = 1.f + eps[l];
  float z = one*hin[(size_t)node*128 + d] + acc;
  zout[(size_t)node*128 + d] = f2bf(z);
}

// GEMM1: y1[N,256] = z_bf16[N,128] @ W1 + b1, with column sum/sumsq atomics
__global__ __launch_bounds__(256) void gemm1_kernel(const unsigned short* __restrict__ A,
                                                    const unsigned short* __restrict__ BT, // [256][128]
                                                    const float* __restrict__ bias,
                                                    float* __restrict__ Y,
                                                    float* __restrict__ sums, float* __restrict__ sqs){
  __shared__ __align__(16) unsigned short Al[128*128];
  __shared__ __align__(16) unsigned short Bl[128*128];
  const int t = threadIdx.x;
  const int rb = blockIdx.x, cb = blockIdx.y;
  for (int it = 0; it < 8; ++it){
    int idx = it*256 + t;
    int row = idx >> 4, ch = idx & 15;
    int grow = rb*128 + row;
    u32x4v v = {0,0,0,0};
    if (grow < NN) v = *(const u32x4v*)(A + (size_t)grow*128 + ch*8);
    *(u32x4v*)((char*)Al + row*256 + ((ch*16) ^ ((row&7)<<4))) = v;
  }
  for (int it = 0; it < 8; ++it){
    int idx = it*256 + t;
    int row = idx >> 4, ch = idx & 15;
    u32x4v v = *(const u32x4v*)(BT + (size_t)(cb*128 + row)*128 + ch*8);
    *(u32x4v*)((char*)Bl + row*256 + ((ch*16) ^ ((row&7)<<4))) = v;
  }
  __syncthreads();
  const int lane = t & 63, wave = t >> 6;
  const int wm = wave >> 1, wn = wave & 1;
  const int r0 = lane & 15, kg = lane >> 4;
  f32x4v acc[4][4] = {};
  #pragma unroll
  for (int kk = 0; kk < 4; ++kk){
    const int kb = kk*64 + kg*16;
    bf16x8 a[4], b[4];
    #pragma unroll
    for (int m = 0; m < 4; ++m){
      int row = wm*64 + m*16 + r0;
      a[m] = *(const bf16x8*)((const char*)Al + row*256 + (kb ^ ((r0&7)<<4)));
    }
    #pragma unroll
    for (int n = 0; n < 4; ++n){
      int col = wn*64 + n*16 + r0;
      b[n] = *(const bf16x8*)((const char*)Bl + col*256 + (kb ^ ((r0&7)<<4)));
    }
    #pragma unroll
    for (int m = 0; m < 4; ++m)
      #pragma unroll
      for (int n = 0; n < 4; ++n)
        acc[m][n] = __builtin_amdgcn_mfma_f32_16x16x32_bf16(a[m], b[n], acc[m][n], 0, 0, 0);
  }
  #pragma unroll
  for (int n = 0; n < 4; ++n){
    const int col = cb*128 + wn*64 + n*16 + r0;
    const float bv = bias[col];
    float s = 0.f, q = 0.f;
    #pragma unroll
    for (int m = 0; m < 4; ++m){
      const int rowb = rb*128 + wm*64 + m*16 + kg*4;
      #pragma unroll
      for (int j = 0; j < 4; ++j){
        int grow = rowb + j;
        if (grow < NN){
          float v = acc[m][n][j] + bv;
          Y[(size_t)grow*256 + col] = v;
          s += v; q += v*v;
        }
      }
    }
    s += __shfl_xor(s, 16); q += __shfl_xor(q, 16);
    s += __shfl_xor(s, 32); q += __shfl_xor(q, 32);
    if (kg == 0){ atomicAdd(&sums[col], s); atomicAdd(&sqs[col], q); }
  }
}

// GEMM2: y2[N,128] = bnrelu(y1)[N,256] @ W2 + b2, with column stats
__global__ __launch_bounds__(256) void gemm2_kernel(const float* __restrict__ Yin,
                                                    const float* __restrict__ scl, const float* __restrict__ shf,
                                                    const unsigned short* __restrict__ BT, // [128][256]
                                                    const float* __restrict__ bias,
                                                    float* __restrict__ Y,
                                                    float* __restrict__ sums, float* __restrict__ sqs){
  __shared__ __align__(16) unsigned short Al[128*128];
  __shared__ __align__(16) unsigned short Bl[128*128];
  __shared__ float s_scl[256], s_shf[256];
  const int t = threadIdx.x;
  const int rb = blockIdx.x;
  if (t < 256){ s_scl[t] = scl[t]; s_shf[t] = shf[t]; }
  const int lane = t & 63, wave = t >> 6;
  const int wm = wave >> 1, wn = wave & 1;
  const int r0 = lane & 15, kg = lane >> 4;
  f32x4v acc[4][4] = {};
  for (int kt = 0; kt < 2; ++kt){
    __syncthreads();   // kt=0: guards s_scl; kt=1: guards LDS reuse
    for (int it = 0; it < 8; ++it){
      int idx = it*256 + t;
      int row = idx >> 4, ch = idx & 15;
      int grow = rb*128 + row;
      int c0 = kt*128 + ch*8;
      u32x4v pv = {0,0,0,0};
      if (grow < NN){
        f32x4v ya = *(const f32x4v*)(Yin + (size_t)grow*256 + c0);
        f32x4v yb = *(const f32x4v*)(Yin + (size_t)grow*256 + c0 + 4);
        unsigned short tb[8];
        #pragma unroll
        for (int jj = 0; jj < 4; ++jj){
          float a = ya[jj]*s_scl[c0+jj] + s_shf[c0+jj];
          tb[jj] = f2bf(a > 0.f ? a : 0.f);
        }
        #pragma unroll
        for (int jj = 0; jj < 4; ++jj){
          float a = yb[jj]*s_scl[c0+4+jj] + s_shf[c0+4+jj];
          tb[4+jj] = f2bf(a > 0.f ? a : 0.f);
        }
        pv[0] = (uint32_t)tb[0] | ((uint32_t)tb[1] << 16);
        pv[1] = (uint32_t)tb[2] | ((uint32_t)tb[3] << 16);
        pv[2] = (uint32_t)tb[4] | ((uint32_t)tb[5] << 16);
        pv[3] = (uint32_t)tb[6] | ((uint32_t)tb[7] << 16);
      }
      *(u32x4v*)((char*)Al + row*256 + ((ch*16) ^ ((row&7)<<4))) = pv;
    }
    for (int it = 0; it < 8; ++it){
      int idx = it*256 + t;
      int row = idx >> 4, ch = idx & 15;
      u32x4v v = *(const u32x4v*)(BT + (size_t)row*256 + kt*128 + ch*8);
      *(u32x4v*)((char*)Bl + row*256 + ((ch*16) ^ ((row&7)<<4))) = v;
    }
    __syncthreads();
    #pragma unroll
    for (int kk = 0; kk < 4; ++kk){
      const int kb = kk*64 + kg*16;
      bf16x8 a[4], b[4];
      #pragma unroll
      for (int m = 0; m < 4; ++m){
        int row = wm*64 + m*16 + r0;
        a[m] = *(const bf16x8*)((const char*)Al + row*256 + (kb ^ ((r0&7)<<4)));
      }
      #pragma unroll
      for (int n = 0; n < 4; ++n){
        int col = wn*64 + n*16 + r0;
        b[n] = *(const bf16x8*)((const char*)Bl + col*256 + (kb ^ ((r0&7)<<4)));
      }
      #pragma unroll
      for (int m = 0; m < 4; ++m)
        #pragma unroll
        for (int n = 0; n < 4; ++n)
          acc[m][n] = __builtin_amdgcn_mfma_f32_16x16x32_bf16(a[m], b[n], acc[m][n], 0, 0, 0);
    }
  }
  #pragma unroll
  for (int n = 0; n < 4; ++n){
    const int col = wn*64 + n*16 + r0;
    const float bv = bias[col];
    float s = 0.f, q = 0.f;
    #pragma unroll
    for (int m = 0; m < 4; ++m){
      const int rowb = rb*128 + wm*64 + m*16 + kg*4;
      #pragma unroll
      for (int j = 0; j < 4; ++j){
        int grow = rowb + j;
        if (grow < NN){
          float v = acc[m][n][j] + bv;
          Y[(size_t)grow*128 + col] = v;
          s += v; q += v*v;
        }
      }
    }
    s += __shfl_xor(s, 16); q += __shfl_xor(q, 16);
    s += __shfl_xor(s, 32); q += __shfl_xor(q, 32);
    if (kg == 0){ atomicAdd(&sums[col], s); atomicAdd(&sqs[col], q); }
  }
}

__global__ void bnfin_kernel(const float* __restrict__ sums, const float* __restrict__ sqs,
                             const float* __restrict__ g, const float* __restrict__ b,
                             float* __restrict__ scl, float* __restrict__ shf, int C, float invcnt){
  int c = blockIdx.x*blockDim.x + threadIdx.x;
  if (c < C){
    float m = sums[c]*invcnt;
    float v = sqs[c]*invcnt - m*m;
    v = v > 0.f ? v : 0.f;
    float inv = rsqrtf(v + 1e-5f);
    float s = g[c]*inv;
    scl[c] = s;
    shf[c] = b[c] - m*s;
  }
}

__global__ __launch_bounds__(256) void happly_kernel(const float* __restrict__ y2, const float* __restrict__ scl,
                                                     const float* __restrict__ shf, float* __restrict__ h, int relu){
  int idx = blockIdx.x*256 + threadIdx.x;
  if (idx >= NN*32) return;
  int c4 = idx & 31;
  f32x4v y = *(const f32x4v*)(y2 + (size_t)idx*4);
  f32x4v s = *(const f32x4v*)(scl + (size_t)c4*4);
  f32x4v t = *(const f32x4v*)(shf + (size_t)c4*4);
  f32x4v o;
  #pragma unroll
  for (int j = 0; j < 4; ++j){
    float v = y[j]*s[j] + t[j];
    o[j] = (relu && v < 0.f) ? 0.f : v;
  }
  *(f32x4v*)(h + (size_t)idx*4) = o;
}

__global__ __launch_bounds__(128) void pool_kernel(const float* __restrict__ hin, const int* __restrict__ gstart,
                                                   const float* __restrict__ vn, float* __restrict__ vout){
  int g = blockIdx.x, d = threadIdx.x;
  int s = gstart[g], e = gstart[g+1];
  float acc = 0.f;
  for (int r = s; r < e; ++r) acc += hin[(size_t)r*128 + d];
  vout[g*128 + d] = vn[g*128 + d] + acc;
}

__global__ __launch_bounds__(256) void vmlp1_kernel(const float* __restrict__ V, const float* __restrict__ W,
                                                    const float* __restrict__ bias, float* __restrict__ Yo,
                                                    float* __restrict__ sums, float* __restrict__ sqs){
  __shared__ float vrow[128];
  int r = blockIdx.x, c = threadIdx.x;
  if (c < 128) vrow[c] = V[r*128 + c];
  __syncthreads();
  float acc = 0.f;
  #pragma unroll 8
  for (int k = 0; k < 128; ++k) acc += vrow[k]*W[k*256 + c];
  float y = acc + bias[c];
  Yo[r*256 + c] = y;
  atomicAdd(&sums[c], y);
  atomicAdd(&sqs[c], y*y);
}

__global__ __launch_bounds__(128) void vmlp2_kernel(const float* __restrict__ Yin, const float* __restrict__ scl,
                                                    const float* __restrict__ shf, const float* __restrict__ W,
                                                    const float* __restrict__ bias, float* __restrict__ Yo,
                                                    float* __restrict__ sums, float* __restrict__ sqs){
  __shared__ float arow[256];
  int r = blockIdx.x, c = threadIdx.x;
  for (int k = c; k < 256; k += 128){
    float a = Yin[r*256 + k]*scl[k] + shf[k];
    arow[k] = a > 0.f ? a : 0.f;
  }
  __syncthreads();
  float acc = 0.f;
  #pragma unroll 8
  for (int k = 0; k < 256; ++k) acc += arow[k]*W[k*128 + c];
  float y = acc + bias[c];
  Yo[r*128 + c] = y;
  atomicAdd(&sums[c], y);
  atomicAdd(&sqs[c], y*y);
}

__global__ __launch_bounds__(256) void va_kernel(const float* __restrict__ yv2, const float* __restrict__ scl,
                                                 const float* __restrict__ shf, float* __restrict__ vn){
  int idx = blockIdx.x*256 + threadIdx.x;
  if (idx < GG*128){
    int c = idx & 127;
    float v = yv2[idx]*scl[c] + shf[c];
    vn[idx] = v > 0.f ? v : 0.f;
  }
}

// ---------------- launch ----------------

extern "C" void kernel_launch(void* const* d_in, const int* in_sizes, int n_in,
                              void* d_out, int out_size, void* d_ws, size_t ws_size,
                              hipStream_t stream){
  const int*   x         = (const int*)  d_in[0];
  const int*   ei        = (const int*)  d_in[1];
  const float* edge_attr = (const float*)d_in[2];
  const int*   batch     = (const int*)  d_in[3];
  const float* node_emb  = (const float*)d_in[4];
  const float* vn_emb    = (const float*)d_in[5];
  const float* eps       = (const float*)d_in[6];
  const float* edge_W    = (const float*)d_in[7];
  const float* edge_b    = (const float*)d_in[8];
  const float* W1        = (const float*)d_in[9];
  const float* b1        = (const float*)d_in[10];
  const float* bn1_g     = (const float*)d_in[11];
  const float* bn1_b     = (const float*)d_in[12];
  const float* W2        = (const float*)d_in[13];
  const float* b2        = (const float*)d_in[14];
  const float* bn_g      = (const float*)d_in[15];
  const float* bn_b      = (const float*)d_in[16];
  const float* vn_W1     = (const float*)d_in[17];
  const float* vn_b1     = (const float*)d_in[18];
  const float* vn_bn1_g  = (const float*)d_in[19];
  const float* vn_bn1_b  = (const float*)d_in[20];
  const float* vn_W2     = (const float*)d_in[21];
  const float* vn_b2     = (const float*)d_in[22];
  const float* vn_bn2_g  = (const float*)d_in[23];
  const float* vn_bn2_b  = (const float*)d_in[24];
  float* h = (float*)d_out;

  char* ws = (char*)d_ws;
  size_t off = 0;
  auto alloc = [&](size_t bytes)->char*{
    char* p = ws + off; off += (bytes + 255) & ~(size_t)255; return p;
  };
  float*          hin    = (float*)         alloc((size_t)NN*DD*4);
  float*          y1     = (float*)         alloc((size_t)NN*D2*4);
  float*          y2     = (float*)         alloc((size_t)NN*DD*4);
  unsigned short* zbuf   = (unsigned short*)alloc((size_t)NN*DD*2);
  float*          vn     = (float*)         alloc((size_t)GG*DD*4);
  float*          vbuf   = (float*)         alloc((size_t)GG*DD*4);
  float*          yv1    = (float*)         alloc((size_t)GG*D2*4);
  float*          yv2    = (float*)         alloc((size_t)GG*DD*4);
  unsigned short* W1T    = (unsigned short*)alloc((size_t)LL*D2*DD*2);
  unsigned short* W2T    = (unsigned short*)alloc((size_t)LL*D2*DD*2);
  float*          stats  = (float*)         alloc(16*256*4);
  int*            counts = (int*)           alloc((size_t)NN*4);
  int*            startp = (int*)           alloc((size_t)(NN+1)*4);
  int*            cursor = (int*)           alloc((size_t)NN*4);
  int*            csr    = (int*)           alloc((size_t)EE*4);
  int*            bsums  = (int*)           alloc(128*4);
  int*            gstart = (int*)           alloc((GG+1)*4);

  float* sum1 = stats + 0*256,  *sq1 = stats + 1*256,  *scale1 = stats + 2*256,  *shift1 = stats + 3*256;
  float* sum2 = stats + 4*256,  *sq2 = stats + 5*256,  *scale2 = stats + 6*256,  *shift2 = stats + 7*256;
  float* sumv1= stats + 8*256,  *sqv1= stats + 9*256,  *scalev1= stats + 10*256, *shiftv1= stats + 11*256;
  float* sumv2= stats + 12*256, *sqv2= stats + 13*256, *scalev2= stats + 14*256, *shiftv2= stats + 15*256;

  const int nb_scan = (NN + SCAN_B - 1)/SCAN_B;   // 98
  const int ew_blocks = (NN*32 + 255)/256;         // 6250

  // ---- setup: CSR by dst, graph starts, embed, vn init, weight transpose ----
  zero_kernel<<<(NN+255)/256, 256, 0, stream>>>((float*)counts, NN);
  count_kernel<<<EE/256, 256, 0, stream>>>(ei, counts);
  scan1_kernel<<<nb_scan, SCAN_B, 0, stream>>>(counts, bsums, NN);
  scan2_kernel<<<1, 64, 0, stream>>>(bsums, nb_scan);
  scan3_kernel<<<nb_scan, SCAN_B, 0, stream>>>(counts, bsums, startp, cursor, NN);
  fill_kernel<<<EE/256, 256, 0, stream>>>(ei, cursor, csr);
  gstart_kernel<<<1, 256, 0, stream>>>(batch, gstart);
  embed_kernel<<<ew_blocks, 256, 0, stream>>>(x, node_emb, h);
  vninit_kernel<<<(GG*32 + 255)/256, 256, 0, stream>>>(vn_emb, vn);
  wtrans_kernel<<<(2*LL*DD*D2 + 255)/256, 256, 0, stream>>>(W1, W2, W1T, W2T);

  for (int l = 0; l < LL; ++l){
    zero_kernel<<<16, 256, 0, stream>>>(stats, 16*256);
    hin_kernel<<<ew_blocks, 256, 0, stream>>>(h, vn, batch, hin);
    agg_kernel<<<NN, 128, 0, stream>>>(hin, csr, startp, ei, edge_attr,
                                       edge_W + (size_t)l*7*DD, edge_b + (size_t)l*DD, eps, l, zbuf);
    gemm1_kernel<<<dim3((NN+127)/128, 2), 256, 0, stream>>>(zbuf, W1T + (size_t)l*32768,
                                                            b1 + (size_t)l*D2, y1, sum1, sq1);
    bnfin_kernel<<<1, 256, 0, stream>>>(sum1, sq1, bn1_g + (size_t)l*D2, bn1_b + (size_t)l*D2,
                                        scale1, shift1, D2, 1.f/(float)NN);
    gemm2_kernel<<<(NN+127)/128, 256, 0, stream>>>(y1, scale1, shift1, W2T + (size_t)l*32768,
                                                   b2 + (size_t)l*DD, y2, sum2, sq2);
    bnfin_kernel<<<1, 256, 0, stream>>>(sum2, sq2, bn_g + (size_t)l*DD, bn_b + (size_t)l*DD,
                                        scale2, shift2, DD, 1.f/(float)NN);
    happly_kernel<<<ew_blocks, 256, 0, stream>>>(y2, scale2, shift2, h, (l != LL-1) ? 1 : 0);
    if (l < LL-1){
      pool_kernel<<<GG, 128, 0, stream>>>(hin, gstart, vn, vbuf);
      vmlp1_kernel<<<GG, 256, 0, stream>>>(vbuf, vn_W1 + (size_t)l*DD*D2, vn_b1 + (size_t)l*D2,
                                           yv1, sumv1, sqv1);
      bnfin_kernel<<<1, 256, 0, stream>>>(sumv1, sqv1, vn_bn1_g + (size_t)l*D2, vn_bn1_b + (size_t)l*D2,
                                          scalev1, shiftv1, D2, 1.f/(float)GG);
      vmlp2_kernel<<<GG, 128, 0, stream>>>(yv1, scalev1, shiftv1, vn_W2 + (size_t)l*D2*DD,
                                           vn_b2 + (size_t)l*DD, yv2, sumv2, sqv2);
      bnfin_kernel<<<1, 256, 0, stream>>>(sumv2, sqv2, vn_bn2_g + (size_t)l*DD, vn_bn2_b + (size_t)l*DD,
                                          scalev2, shiftv2, DD, 1.f/(float)GG);
      va_kernel<<<(GG*DD + 255)/256, 256, 0, stream>>>(yv2, scalev2, shiftv2, vn);
    }
  }
  (void)in_sizes; (void)n_in; (void)out_size; (void)ws_size;
}

// Round 2
// 1373.984 us; speedup vs baseline: 1.2187x; 1.2187x over previous
//
#include <hip/hip_runtime.h>
#include <stdint.h>

#define NN 50000
#define EE 640000
#define DD 128
#define LL 5
#define GG 128
#define D2 256

using bf16x8 = __attribute__((ext_vector_type(8))) short;
using f32x4v = __attribute__((ext_vector_type(4))) float;
using u32x4v = __attribute__((ext_vector_type(4))) unsigned int;

__device__ __forceinline__ unsigned short f2bf(float f){
  union { float f; uint32_t u; } c; c.f = f;
  uint32_t u = c.u;
  uint32_t r = (u + 0x7FFFu + ((u >> 16) & 1u)) >> 16;
  return (unsigned short)r;
}

// ---------------- setup kernels ----------------

__global__ __launch_bounds__(256) void zero_kernel(float* p, int n){
  int i = blockIdx.x*256 + threadIdx.x;
  if (i < n) p[i] = 0.f;
}

__global__ __launch_bounds__(256) void count_kernel(const int* __restrict__ ei, int* __restrict__ counts){
  int e = blockIdx.x*256 + threadIdx.x;
  if (e < EE) atomicAdd(&counts[ei[EE + e]], 1);
}

#define SCAN_B 512
__global__ __launch_bounds__(SCAN_B) void scan1_kernel(const int* __restrict__ counts, int* __restrict__ bsums, int n){
  __shared__ int sh[SCAN_B];
  int b = blockIdx.x, t = threadIdx.x;
  int i = b*SCAN_B + t;
  sh[t] = (i < n) ? counts[i] : 0;
  __syncthreads();
  for (int s = SCAN_B/2; s > 0; s >>= 1){
    if (t < s) sh[t] += sh[t+s];
    __syncthreads();
  }
  if (t == 0) bsums[b] = sh[0];
}

__global__ void scan2_kernel(int* bsums, int nb){
  if (threadIdx.x == 0){
    int run = 0;
    for (int i = 0; i < nb; ++i){ int v = bsums[i]; bsums[i] = run; run += v; }
  }
}

__global__ __launch_bounds__(SCAN_B) void scan3_kernel(const int* __restrict__ counts, const int* __restrict__ bsums,
                                                       int* __restrict__ startp, int* __restrict__ cursor, int n){
  __shared__ int sh[SCAN_B];
  int b = blockIdx.x, t = threadIdx.x;
  int i = b*SCAN_B + t;
  int v = (i < n) ? counts[i] : 0;
  sh[t] = v;
  __syncthreads();
  for (int s = 1; s < SCAN_B; s <<= 1){
    int add = (t >= s) ? sh[t-s] : 0;
    __syncthreads();
    sh[t] += add;
    __syncthreads();
  }
  int excl = sh[t] - v + bsums[b];
  if (i < n){ startp[i] = excl; cursor[i] = excl; }
  if (i == n-1) startp[n] = excl + v;
}

__global__ __launch_bounds__(256) void fill_kernel(const int* __restrict__ ei, int* __restrict__ cursor, int* __restrict__ csr){
  int e = blockIdx.x*256 + threadIdx.x;
  if (e < EE){
    int d = ei[EE + e];
    int slot = atomicAdd(&cursor[d], 1);
    csr[slot] = e;
  }
}

__global__ __launch_bounds__(256) void embed_kernel(const int* __restrict__ x, const float* __restrict__ emb, float* __restrict__ h){
  int idx = blockIdx.x*256 + threadIdx.x;
  if (idx >= NN*32) return;
  int i = idx >> 5, c4 = idx & 31;
  int xi = x[i];
  *(f32x4v*)(h + (size_t)idx*4) = *(const f32x4v*)(emb + ((size_t)xi*32 + c4)*4);
}

__global__ __launch_bounds__(256) void vninit_kernel(const float* __restrict__ vn_emb, float* __restrict__ vn){
  int idx = blockIdx.x*256 + threadIdx.x;
  if (idx >= GG*32) return;
  *(f32x4v*)(vn + (size_t)idx*4) = *(const f32x4v*)(vn_emb + (size_t)(idx & 31)*4);
}

__global__ __launch_bounds__(256) void wtrans_kernel(const float* __restrict__ W1, const float* __restrict__ W2,
                                                     unsigned short* __restrict__ W1T, unsigned short* __restrict__ W2T){
  int idx = blockIdx.x*256 + threadIdx.x;
  const int total = LL*DD*D2;
  if (idx < total){
    int l = idx / (DD*D2);
    int rem = idx - l*(DD*D2);
    int k = rem / D2;          // 0..127 input dim
    int c = rem - k*D2;        // 0..255 output col
    W1T[(size_t)l*32768 + (size_t)c*128 + k] = f2bf(W1[idx]);
  } else if (idx < 2*total){
    int j = idx - total;
    int l = j / (DD*D2);
    int rem = j - l*(DD*D2);
    int k = rem / DD;          // 0..255 input dim
    int c = rem - k*DD;        // 0..127 output col
    W2T[(size_t)l*32768 + (size_t)c*256 + k] = f2bf(W2[j]);
  }
}

// ---------------- per-layer kernels ----------------

__global__ __launch_bounds__(256) void hin_kernel(const float* __restrict__ h, const float* __restrict__ vn,
                                                  const int* __restrict__ batch, float* __restrict__ hin){
  int idx = blockIdx.x*256 + threadIdx.x;
  if (idx >= NN*32) return;
  int i = idx >> 5, c4 = idx & 31;
  int b = batch[i];
  f32x4v hv = *(const f32x4v*)(h + (size_t)idx*4);
  f32x4v vv = *(const f32x4v*)(vn + ((size_t)b*32 + c4)*4);
  *(f32x4v*)(hin + (size_t)idx*4) = hv + vv;
}

// block per dst node; thread d owns feature d. Computes z = (1+eps)*hin + sum_e relu(hin[src]+edgeMLP) -> bf16
__global__ __launch_bounds__(128) void agg_kernel(const float* __restrict__ hin, const int* __restrict__ csr,
                                                  const int* __restrict__ startp, const int* __restrict__ ei,
                                                  const float* __restrict__ ea, const float* __restrict__ eW,
                                                  const float* __restrict__ eb, const float* __restrict__ eps, int l,
                                                  unsigned short* __restrict__ zout){
  int node = blockIdx.x, d = threadIdx.x;
  int s0 = startp[node], s1 = startp[node+1];
  float w[7];
  #pragma unroll
  for (int k = 0; k < 7; ++k) w[k] = eW[k*128 + d];
  float bd = eb[d];
  float acc = 0.f;
  __shared__ int eids[32];
  __shared__ int srcs[32];
  __shared__ float eav[32][8];
  for (int base = s0; base < s1; base += 32){
    int cnt = min(32, s1 - base);
    __syncthreads();
    if (d < cnt){ int e = csr[base + d]; eids[d] = e; srcs[d] = ei[e]; }
    __syncthreads();
    for (int q = d; q < cnt*7; q += 128){
      int j = q / 7, k = q - j*7;
      eav[j][k] = ea[(size_t)eids[j]*7 + k];
    }
    __syncthreads();
    for (int j = 0; j < cnt; ++j){
      float hv = hin[(size_t)srcs[j]*128 + d];
      float e = bd;
      #pragma unroll
      for (int k = 0; k < 7; ++k) e += eav[j][k]*w[k];
      float m = hv + e;
      acc += (m > 0.f) ? m : 0.f;
    }
  }
  float one = 1.f + eps[l];
  float z = one*hin[(size_t)node*128 + d] + acc;
  zout[(size_t)node*128 + d] = f2bf(z);
}

// GEMM1: y1[N,256] = z_bf16[N,128] @ W1 + b1, with column sum/sumsq atomics
__global__ __launch_bounds__(256) void gemm1_kernel(const unsigned short* __restrict__ A,
                                                    const unsigned short* __restrict__ BT, // [256][128]
                                                    const float* __restrict__ bias,
                                                    float* __restrict__ Y,
                                                    float* __restrict__ sums, float* __restrict__ sqs){
  __shared__ __align__(16) unsigned short Al[128*128];
  __shared__ __align__(16) unsigned short Bl[128*128];
  const int t = threadIdx.x;
  const int rb = blockIdx.x, cb = blockIdx.y;
  for (int it = 0; it < 8; ++it){
    int idx = it*256 + t;
    int row = idx >> 4, ch = idx & 15;
    int grow = rb*128 + row;
    u32x4v v = {0,0,0,0};
    if (grow < NN) v = *(const u32x4v*)(A + (size_t)grow*128 + ch*8);
    *(u32x4v*)((char*)Al + row*256 + ((ch*16) ^ ((row&7)<<4))) = v;
  }
  for (int it = 0; it < 8; ++it){
    int idx = it*256 + t;
    int row = idx >> 4, ch = idx & 15;
    u32x4v v = *(const u32x4v*)(BT + (size_t)(cb*128 + row)*128 + ch*8);
    *(u32x4v*)((char*)Bl + row*256 + ((ch*16) ^ ((row&7)<<4))) = v;
  }
  __syncthreads();
  const int lane = t & 63, wave = t >> 6;
  const int wm = wave >> 1, wn = wave & 1;
  const int r0 = lane & 15, kg = lane >> 4;
  f32x4v acc[4][4] = {};
  #pragma unroll
  for (int kk = 0; kk < 4; ++kk){
    const int kb = kk*64 + kg*16;
    bf16x8 a[4], b[4];
    #pragma unroll
    for (int m = 0; m < 4; ++m){
      int row = wm*64 + m*16 + r0;
      a[m] = *(const bf16x8*)((const char*)Al + row*256 + (kb ^ ((r0&7)<<4)));
    }
    #pragma unroll
    for (int n = 0; n < 4; ++n){
      int col = wn*64 + n*16 + r0;
      b[n] = *(const bf16x8*)((const char*)Bl + col*256 + (kb ^ ((r0&7)<<4)));
    }
    #pragma unroll
    for (int m = 0; m < 4; ++m)
      #pragma unroll
      for (int n = 0; n < 4; ++n)
        acc[m][n] = __builtin_amdgcn_mfma_f32_16x16x32_bf16(a[m], b[n], acc[m][n], 0, 0, 0);
  }
  #pragma unroll
  for (int n = 0; n < 4; ++n){
    const int col = cb*128 + wn*64 + n*16 + r0;
    const float bv = bias[col];
    float s = 0.f, q = 0.f;
    #pragma unroll
    for (int m = 0; m < 4; ++m){
      const int rowb = rb*128 + wm*64 + m*16 + kg*4;
      #pragma unroll
      for (int j = 0; j < 4; ++j){
        int grow = rowb + j;
        if (grow < NN){
          float v = acc[m][n][j] + bv;
          Y[(size_t)grow*256 + col] = v;
          s += v; q += v*v;
        }
      }
    }
    s += __shfl_xor(s, 16); q += __shfl_xor(q, 16);
    s += __shfl_xor(s, 32); q += __shfl_xor(q, 32);
    if (kg == 0){ atomicAdd(&sums[col], s); atomicAdd(&sqs[col], q); }
  }
}

// GEMM2: y2[N,128] = bnrelu(y1)[N,256] @ W2 + b2, with column stats
__global__ __launch_bounds__(256) void gemm2_kernel(const float* __restrict__ Yin,
                                                    const float* __restrict__ scl, const float* __restrict__ shf,
                                                    const unsigned short* __restrict__ BT, // [128][256]
                                                    const float* __restrict__ bias,
                                                    float* __restrict__ Y,
                                                    float* __restrict__ sums, float* __restrict__ sqs){
  __shared__ __align__(16) unsigned short Al[128*128];
  __shared__ __align__(16) unsigned short Bl[128*128];
  __shared__ float s_scl[256], s_shf[256];
  const int t = threadIdx.x;
  const int rb = blockIdx.x;
  if (t < 256){ s_scl[t] = scl[t]; s_shf[t] = shf[t]; }
  const int lane = t & 63, wave = t >> 6;
  const int wm = wave >> 1, wn = wave & 1;
  const int r0 = lane & 15, kg = lane >> 4;
  f32x4v acc[4][4] = {};
  for (int kt = 0; kt < 2; ++kt){
    __syncthreads();   // kt=0: guards s_scl; kt=1: guards LDS reuse
    for (int it = 0; it < 8; ++it){
      int idx = it*256 + t;
      int row = idx >> 4, ch = idx & 15;
      int grow = rb*128 + row;
      int c0 = kt*128 + ch*8;
      u32x4v pv = {0,0,0,0};
      if (grow < NN){
        f32x4v ya = *(const f32x4v*)(Yin + (size_t)grow*256 + c0);
        f32x4v yb = *(const f32x4v*)(Yin + (size_t)grow*256 + c0 + 4);
        unsigned short tb[8];
        #pragma unroll
        for (int jj = 0; jj < 4; ++jj){
          float a = ya[jj]*s_scl[c0+jj] + s_shf[c0+jj];
          tb[jj] = f2bf(a > 0.f ? a : 0.f);
        }
        #pragma unroll
        for (int jj = 0; jj < 4; ++jj){
          float a = yb[jj]*s_scl[c0+4+jj] + s_shf[c0+4+jj];
          tb[4+jj] = f2bf(a > 0.f ? a : 0.f);
        }
        pv[0] = (uint32_t)tb[0] | ((uint32_t)tb[1] << 16);
        pv[1] = (uint32_t)tb[2] | ((uint32_t)tb[3] << 16);
        pv[2] = (uint32_t)tb[4] | ((uint32_t)tb[5] << 16);
        pv[3] = (uint32_t)tb[6] | ((uint32_t)tb[7] << 16);
      }
      *(u32x4v*)((char*)Al + row*256 + ((ch*16) ^ ((row&7)<<4))) = pv;
    }
    for (int it = 0; it < 8; ++it){
      int idx = it*256 + t;
      int row = idx >> 4, ch = idx & 15;
      u32x4v v = *(const u32x4v*)(BT + (size_t)row*256 + kt*128 + ch*8);
      *(u32x4v*)((char*)Bl + row*256 + ((ch*16) ^ ((row&7)<<4))) = v;
    }
    __syncthreads();
    #pragma unroll
    for (int kk = 0; kk < 4; ++kk){
      const int kb = kk*64 + kg*16;
      bf16x8 a[4], b[4];
      #pragma unroll
      for (int m = 0; m < 4; ++m){
        int row = wm*64 + m*16 + r0;
        a[m] = *(const bf16x8*)((const char*)Al + row*256 + (kb ^ ((r0&7)<<4)));
      }
      #pragma unroll
      for (int n = 0; n < 4; ++n){
        int col = wn*64 + n*16 + r0;
        b[n] = *(const bf16x8*)((const char*)Bl + col*256 + (kb ^ ((r0&7)<<4)));
      }
      #pragma unroll
      for (int m = 0; m < 4; ++m)
        #pragma unroll
        for (int n = 0; n < 4; ++n)
          acc[m][n] = __builtin_amdgcn_mfma_f32_16x16x32_bf16(a[m], b[n], acc[m][n], 0, 0, 0);
    }
  }
  #pragma unroll
  for (int n = 0; n < 4; ++n){
    const int col = wn*64 + n*16 + r0;
    const float bv = bias[col];
    float s = 0.f, q = 0.f;
    #pragma unroll
    for (int m = 0; m < 4; ++m){
      const int rowb = rb*128 + wm*64 + m*16 + kg*4;
      #pragma unroll
      for (int j = 0; j < 4; ++j){
        int grow = rowb + j;
        if (grow < NN){
          float v = acc[m][n][j] + bv;
          Y[(size_t)grow*128 + col] = v;
          s += v; q += v*v;
        }
      }
    }
    s += __shfl_xor(s, 16); q += __shfl_xor(q, 16);
    s += __shfl_xor(s, 32); q += __shfl_xor(q, 32);
    if (kg == 0){ atomicAdd(&sums[col], s); atomicAdd(&sqs[col], q); }
  }
}

__global__ void bnfin_kernel(const float* __restrict__ sums, const float* __restrict__ sqs,
                             const float* __restrict__ g, const float* __restrict__ b,
                             float* __restrict__ scl, float* __restrict__ shf, int C, float invcnt){
  int c = blockIdx.x*blockDim.x + threadIdx.x;
  if (c < C){
    float m = sums[c]*invcnt;
    float v = sqs[c]*invcnt - m*m;
    v = v > 0.f ? v : 0.f;
    float inv = rsqrtf(v + 1e-5f);
    float s = g[c]*inv;
    scl[c] = s;
    shf[c] = b[c] - m*s;
  }
}

__global__ __launch_bounds__(256) void happly_kernel(const float* __restrict__ y2, const float* __restrict__ scl,
                                                     const float* __restrict__ shf, float* __restrict__ h, int relu){
  int idx = blockIdx.x*256 + threadIdx.x;
  if (idx >= NN*32) return;
  int c4 = idx & 31;
  f32x4v y = *(const f32x4v*)(y2 + (size_t)idx*4);
  f32x4v s = *(const f32x4v*)(scl + (size_t)c4*4);
  f32x4v t = *(const f32x4v*)(shf + (size_t)c4*4);
  f32x4v o;
  #pragma unroll
  for (int j = 0; j < 4; ++j){
    float v = y[j]*s[j] + t[j];
    o[j] = (relu && v < 0.f) ? 0.f : v;
  }
  *(f32x4v*)(h + (size_t)idx*4) = o;
}

// vbuf = vn  (pool accumulates on top with atomics)
__global__ __launch_bounds__(256) void vcopy_kernel(const float* __restrict__ vn, float* __restrict__ vbuf){
  int idx = blockIdx.x*256 + threadIdx.x;
  if (idx < GG*DD) vbuf[idx] = vn[idx];
}

// parallel pool: block = 128 consecutive nodes, thread d owns feature d.
// batch is sorted -> few group boundaries per block; atomicAdd per run.
#define POOL_ROWS 128
__global__ __launch_bounds__(128) void pool2_kernel(const float* __restrict__ hin, const int* __restrict__ batch,
                                                    float* __restrict__ vout){
  int r0 = blockIdx.x*POOL_ROWS;
  int r1 = r0 + POOL_ROWS; if (r1 > NN) r1 = NN;
  int d = threadIdx.x;
  __shared__ int sb[POOL_ROWS];
  if (r0 + d < r1) sb[d] = batch[r0 + d];
  __syncthreads();
  int curg = sb[0];
  float acc = 0.f;
  for (int r = r0; r < r1; ++r){
    int g = sb[r - r0];
    if (g != curg){
      atomicAdd(&vout[(size_t)curg*DD + d], acc);
      acc = 0.f; curg = g;
    }
    acc += hin[(size_t)r*DD + d];
  }
  atomicAdd(&vout[(size_t)curg*DD + d], acc);
}

__global__ __launch_bounds__(256) void vmlp1_kernel(const float* __restrict__ V, const float* __restrict__ W,
                                                    const float* __restrict__ bias, float* __restrict__ Yo,
                                                    float* __restrict__ sums, float* __restrict__ sqs){
  __shared__ float vrow[128];
  int r = blockIdx.x, c = threadIdx.x;
  if (c < 128) vrow[c] = V[r*128 + c];
  __syncthreads();
  float acc = 0.f;
  #pragma unroll 8
  for (int k = 0; k < 128; ++k) acc += vrow[k]*W[k*256 + c];
  float y = acc + bias[c];
  Yo[r*256 + c] = y;
  atomicAdd(&sums[c], y);
  atomicAdd(&sqs[c], y*y);
}

__global__ __launch_bounds__(128) void vmlp2_kernel(const float* __restrict__ Yin, const float* __restrict__ scl,
                                                    const float* __restrict__ shf, const float* __restrict__ W,
                                                    const float* __restrict__ bias, float* __restrict__ Yo,
                                                    float* __restrict__ sums, float* __restrict__ sqs){
  __shared__ float arow[256];
  int r = blockIdx.x, c = threadIdx.x;
  for (int k = c; k < 256; k += 128){
    float a = Yin[r*256 + k]*scl[k] + shf[k];
    arow[k] = a > 0.f ? a : 0.f;
  }
  __syncthreads();
  float acc = 0.f;
  #pragma unroll 8
  for (int k = 0; k < 256; ++k) acc += arow[k]*W[k*128 + c];
  float y = acc + bias[c];
  Yo[r*128 + c] = y;
  atomicAdd(&sums[c], y);
  atomicAdd(&sqs[c], y*y);
}

__global__ __launch_bounds__(256) void va_kernel(const float* __restrict__ yv2, const float* __restrict__ scl,
                                                 const float* __restrict__ shf, float* __restrict__ vn){
  int idx = blockIdx.x*256 + threadIdx.x;
  if (idx < GG*128){
    int c = idx & 127;
    float v = yv2[idx]*scl[c] + shf[c];
    vn[idx] = v > 0.f ? v : 0.f;
  }
}

// ---------------- launch ----------------

extern "C" void kernel_launch(void* const* d_in, const int* in_sizes, int n_in,
                              void* d_out, int out_size, void* d_ws, size_t ws_size,
                              hipStream_t stream){
  const int*   x         = (const int*)  d_in[0];
  const int*   ei        = (const int*)  d_in[1];
  const float* edge_attr = (const float*)d_in[2];
  const int*   batch     = (const int*)  d_in[3];
  const float* node_emb  = (const float*)d_in[4];
  const float* vn_emb    = (const float*)d_in[5];
  const float* eps       = (const float*)d_in[6];
  const float* edge_W    = (const float*)d_in[7];
  const float* edge_b    = (const float*)d_in[8];
  const float* W1        = (const float*)d_in[9];
  const float* b1        = (const float*)d_in[10];
  const float* bn1_g     = (const float*)d_in[11];
  const float* bn1_b     = (const float*)d_in[12];
  const float* W2        = (const float*)d_in[13];
  const float* b2        = (const float*)d_in[14];
  const float* bn_g      = (const float*)d_in[15];
  const float* bn_b      = (const float*)d_in[16];
  const float* vn_W1     = (const float*)d_in[17];
  const float* vn_b1     = (const float*)d_in[18];
  const float* vn_bn1_g  = (const float*)d_in[19];
  const float* vn_bn1_b  = (const float*)d_in[20];
  const float* vn_W2     = (const float*)d_in[21];
  const float* vn_b2     = (const float*)d_in[22];
  const float* vn_bn2_g  = (const float*)d_in[23];
  const float* vn_bn2_b  = (const float*)d_in[24];
  float* h = (float*)d_out;

  char* ws = (char*)d_ws;
  size_t off = 0;
  auto alloc = [&](size_t bytes)->char*{
    char* p = ws + off; off += (bytes + 255) & ~(size_t)255; return p;
  };
  float*          hin    = (float*)         alloc((size_t)NN*DD*4);
  float*          y1     = (float*)         alloc((size_t)NN*D2*4);
  float*          y2     = (float*)         alloc((size_t)NN*DD*4);
  unsigned short* zbuf   = (unsigned short*)alloc((size_t)NN*DD*2);
  float*          vn     = (float*)         alloc((size_t)GG*DD*4);
  float*          vbuf   = (float*)         alloc((size_t)GG*DD*4);
  float*          yv1    = (float*)         alloc((size_t)GG*D2*4);
  float*          yv2    = (float*)         alloc((size_t)GG*DD*4);
  unsigned short* W1T    = (unsigned short*)alloc((size_t)LL*D2*DD*2);
  unsigned short* W2T    = (unsigned short*)alloc((size_t)LL*D2*DD*2);
  float*          stats  = (float*)         alloc(16*256*4);
  int*            counts = (int*)           alloc((size_t)NN*4);
  int*            startp = (int*)           alloc((size_t)(NN+1)*4);
  int*            cursor = (int*)           alloc((size_t)NN*4);
  int*            csr    = (int*)           alloc((size_t)EE*4);
  int*            bsums  = (int*)           alloc(128*4);

  float* sum1 = stats + 0*256,  *sq1 = stats + 1*256,  *scale1 = stats + 2*256,  *shift1 = stats + 3*256;
  float* sum2 = stats + 4*256,  *sq2 = stats + 5*256,  *scale2 = stats + 6*256,  *shift2 = stats + 7*256;
  float* sumv1= stats + 8*256,  *sqv1= stats + 9*256,  *scalev1= stats + 10*256, *shiftv1= stats + 11*256;
  float* sumv2= stats + 12*256, *sqv2= stats + 13*256, *scalev2= stats + 14*256, *shiftv2= stats + 15*256;

  const int nb_scan = (NN + SCAN_B - 1)/SCAN_B;   // 98
  const int ew_blocks = (NN*32 + 255)/256;         // 6250
  const int pool_blocks = (NN + POOL_ROWS - 1)/POOL_ROWS;  // 391

  // ---- setup: CSR by dst, embed, vn init, weight transpose ----
  zero_kernel<<<(NN+255)/256, 256, 0, stream>>>((float*)counts, NN);
  count_kernel<<<EE/256, 256, 0, stream>>>(ei, counts);
  scan1_kernel<<<nb_scan, SCAN_B, 0, stream>>>(counts, bsums, NN);
  scan2_kernel<<<1, 64, 0, stream>>>(bsums, nb_scan);
  scan3_kernel<<<nb_scan, SCAN_B, 0, stream>>>(counts, bsums, startp, cursor, NN);
  fill_kernel<<<EE/256, 256, 0, stream>>>(ei, cursor, csr);
  embed_kernel<<<ew_blocks, 256, 0, stream>>>(x, node_emb, h);
  vninit_kernel<<<(GG*32 + 255)/256, 256, 0, stream>>>(vn_emb, vn);
  wtrans_kernel<<<(2*LL*DD*D2 + 255)/256, 256, 0, stream>>>(W1, W2, W1T, W2T);

  for (int l = 0; l < LL; ++l){
    zero_kernel<<<16, 256, 0, stream>>>(stats, 16*256);
    hin_kernel<<<ew_blocks, 256, 0, stream>>>(h, vn, batch, hin);
    agg_kernel<<<NN, 128, 0, stream>>>(hin, csr, startp, ei, edge_attr,
                                       edge_W + (size_t)l*7*DD, edge_b + (size_t)l*DD, eps, l, zbuf);
    gemm1_kernel<<<dim3((NN+127)/128, 2), 256, 0, stream>>>(zbuf, W1T + (size_t)l*32768,
                                                            b1 + (size_t)l*D2, y1, sum1, sq1);
    bnfin_kernel<<<1, 256, 0, stream>>>(sum1, sq1, bn1_g + (size_t)l*D2, bn1_b + (size_t)l*D2,
                                        scale1, shift1, D2, 1.f/(float)NN);
    gemm2_kernel<<<(NN+127)/128, 256, 0, stream>>>(y1, scale1, shift1, W2T + (size_t)l*32768,
                                                   b2 + (size_t)l*DD, y2, sum2, sq2);
    bnfin_kernel<<<1, 256, 0, stream>>>(sum2, sq2, bn_g + (size_t)l*DD, bn_b + (size_t)l*DD,
                                        scale2, shift2, DD, 1.f/(float)NN);
    happly_kernel<<<ew_blocks, 256, 0, stream>>>(y2, scale2, shift2, h, (l != LL-1) ? 1 : 0);
    if (l < LL-1){
      vcopy_kernel<<<(GG*DD + 255)/256, 256, 0, stream>>>(vn, vbuf);
      pool2_kernel<<<pool_blocks, 128, 0, stream>>>(hin, batch, vbuf);
      vmlp1_kernel<<<GG, 256, 0, stream>>>(vbuf, vn_W1 + (size_t)l*DD*D2, vn_b1 + (size_t)l*D2,
                                           yv1, sumv1, sqv1);
      bnfin_kernel<<<1, 256, 0, stream>>>(sumv1, sqv1, vn_bn1_g + (size_t)l*D2, vn_bn1_b + (size_t)l*D2,
                                          scalev1, shiftv1, D2, 1.f/(float)GG);
      vmlp2_kernel<<<GG, 128, 0, stream>>>(yv1, scalev1, shiftv1, vn_W2 + (size_t)l*D2*DD,
                                           vn_b2 + (size_t)l*DD, yv2, sumv2, sqv2);
      bnfin_kernel<<<1, 256, 0, stream>>>(sumv2, sqv2, vn_bn2_g + (size_t)l*DD, vn_bn2_b + (size_t)l*DD,
                                          scalev2, shiftv2, DD, 1.f/(float)GG);
      va_kernel<<<(GG*DD + 255)/256, 256, 0, stream>>>(yv2, scalev2, shiftv2, vn);
    }
  }
  (void)in_sizes; (void)n_in; (void)out_size; (void)ws_size;
}

// Round 4
// 1263.065 us; speedup vs baseline: 1.3257x; 1.0878x over previous
//
#include <hip/hip_runtime.h>
#include <stdint.h>

#define NN 50000
#define EE 640000
#define DD 128
#define LL 5
#define GG 128
#define D2 256

using bf16x8 = __attribute__((ext_vector_type(8))) short;
using f32x4v = __attribute__((ext_vector_type(4))) float;
using u32x4v = __attribute__((ext_vector_type(4))) unsigned int;

__device__ __forceinline__ unsigned short f2bf(float f){
  union { float f; uint32_t u; } c; c.f = f;
  uint32_t u = c.u;
  uint32_t r = (u + 0x7FFFu + ((u >> 16) & 1u)) >> 16;
  return (unsigned short)r;
}
__device__ __forceinline__ float bf2f(unsigned short u){
  union { uint32_t u; float f; } c; c.u = ((uint32_t)u) << 16; return c.f;
}

// ---------------- setup kernels ----------------

__global__ __launch_bounds__(256) void zero_kernel(float* p, int n){
  int i = blockIdx.x*256 + threadIdx.x;
  if (i < n) p[i] = 0.f;
}

__global__ __launch_bounds__(256) void count_kernel(const int* __restrict__ ei, int* __restrict__ counts){
  int e = blockIdx.x*256 + threadIdx.x;
  if (e < EE) atomicAdd(&counts[ei[EE + e]], 1);
}

#define SCAN_B 512
__global__ __launch_bounds__(SCAN_B) void scan1_kernel(const int* __restrict__ counts, int* __restrict__ bsums, int n){
  __shared__ int sh[SCAN_B];
  int b = blockIdx.x, t = threadIdx.x;
  int i = b*SCAN_B + t;
  sh[t] = (i < n) ? counts[i] : 0;
  __syncthreads();
  for (int s = SCAN_B/2; s > 0; s >>= 1){
    if (t < s) sh[t] += sh[t+s];
    __syncthreads();
  }
  if (t == 0) bsums[b] = sh[0];
}

__global__ void scan2_kernel(int* bsums, int nb){
  if (threadIdx.x == 0){
    int run = 0;
    for (int i = 0; i < nb; ++i){ int v = bsums[i]; bsums[i] = run; run += v; }
  }
}

__global__ __launch_bounds__(SCAN_B) void scan3_kernel(const int* __restrict__ counts, const int* __restrict__ bsums,
                                                       int* __restrict__ startp, int* __restrict__ cursor, int n){
  __shared__ int sh[SCAN_B];
  int b = blockIdx.x, t = threadIdx.x;
  int i = b*SCAN_B + t;
  int v = (i < n) ? counts[i] : 0;
  sh[t] = v;
  __syncthreads();
  for (int s = 1; s < SCAN_B; s <<= 1){
    int add = (t >= s) ? sh[t-s] : 0;
    __syncthreads();
    sh[t] += add;
    __syncthreads();
  }
  int excl = sh[t] - v + bsums[b];
  if (i < n){ startp[i] = excl; cursor[i] = excl; }
  if (i == n-1) startp[n] = excl + v;
}

__global__ __launch_bounds__(256) void fill_kernel(const int* __restrict__ ei, int* __restrict__ cursor, int* __restrict__ csr){
  int e = blockIdx.x*256 + threadIdx.x;
  if (e < EE){
    int d = ei[EE + e];
    int slot = atomicAdd(&cursor[d], 1);
    csr[slot] = e;
  }
}

// gather edge_attr + src into CSR order (once) -> streaming reads in agg
__global__ __launch_bounds__(256) void egather_kernel(const int* __restrict__ csr, const int* __restrict__ ei,
                                                      const float* __restrict__ ea,
                                                      int* __restrict__ csr_src, float* __restrict__ csr_ea8){
  int s = blockIdx.x*256 + threadIdx.x;
  if (s < EE){
    int e = csr[s];
    csr_src[s] = ei[e];
    float v[8];
    #pragma unroll
    for (int k = 0; k < 7; ++k) v[k] = ea[(size_t)e*7 + k];
    v[7] = 0.f;
    #pragma unroll
    for (int k = 0; k < 8; ++k) csr_ea8[(size_t)s*8 + k] = v[k];
  }
}

__global__ __launch_bounds__(256) void wtrans_kernel(const float* __restrict__ W1, const float* __restrict__ W2,
                                                     unsigned short* __restrict__ W1T, unsigned short* __restrict__ W2T){
  int idx = blockIdx.x*256 + threadIdx.x;
  const int total = LL*DD*D2;
  if (idx < total){
    int l = idx / (DD*D2);
    int rem = idx - l*(DD*D2);
    int k = rem / D2;
    int c = rem - k*D2;
    W1T[(size_t)l*32768 + (size_t)c*128 + k] = f2bf(W1[idx]);
  } else if (idx < 2*total){
    int j = idx - total;
    int l = j / (DD*D2);
    int rem = j - l*(DD*D2);
    int k = rem / DD;
    int c = rem - k*DD;
    W2T[(size_t)l*32768 + (size_t)c*256 + k] = f2bf(W2[j]);
  }
}

// init: hin0 = emb[x] + vn_emb (bf16), pool0 atomics, block0 writes vn
__global__ __launch_bounds__(128) void init_kernel(const int* __restrict__ x, const int* __restrict__ batch,
                                                   const float* __restrict__ emb, const float* __restrict__ vn_emb,
                                                   unsigned short* __restrict__ hin_bf, float* __restrict__ vbuf0,
                                                   float* __restrict__ vn){
  int r0 = blockIdx.x*128;
  int r1 = r0 + 128; if (r1 > NN) r1 = NN;
  int d = threadIdx.x;
  float ve = vn_emb[d];
  if (blockIdx.x == 0){
    for (int g = 0; g < GG; ++g) vn[(size_t)g*DD + d] = ve;
  }
  __shared__ int sb[128];
  __shared__ int sx[128];
  if (r0 + d < r1){ sb[d] = batch[r0 + d]; sx[d] = x[r0 + d]; }
  __syncthreads();
  int curg = sb[0];
  float pacc = 0.f;
  for (int r = r0; r < r1; ++r){
    int g = sb[r - r0];
    if (g != curg){
      atomicAdd(&vbuf0[(size_t)curg*DD + d], pacc);
      pacc = 0.f; curg = g;
    }
    float hv = emb[(size_t)sx[r - r0]*DD + d] + ve;
    hin_bf[(size_t)r*DD + d] = f2bf(hv);
    pacc += hv;
  }
  atomicAdd(&vbuf0[(size_t)curg*DD + d], pacc);
}

// ---------------- per-layer kernels ----------------

// block per dst node; thread d owns feature d. z = (1+eps)*hin + sum relu(hin[src]+edgeMLP) -> bf16
__global__ __launch_bounds__(128) void agg2_kernel(const unsigned short* __restrict__ hin_bf,
                                                   const int* __restrict__ csr_src, const float* __restrict__ csr_ea8,
                                                   const int* __restrict__ startp,
                                                   const float* __restrict__ eW, const float* __restrict__ eb,
                                                   const float* __restrict__ eps, int l,
                                                   unsigned short* __restrict__ zout){
  int node = blockIdx.x, d = threadIdx.x;
  int s0 = startp[node], s1 = startp[node+1];
  float w[7];
  #pragma unroll
  for (int k = 0; k < 7; ++k) w[k] = eW[k*128 + d];
  float bd = eb[d];
  float acc = 0.f;
  __shared__ int ssrc[32];
  __shared__ float sattr[32][8];
  for (int base = s0; base < s1; base += 32){
    int cnt = min(32, s1 - base);
    __syncthreads();
    if (d < cnt) ssrc[d] = csr_src[base + d];
    for (int q = d; q < cnt*8; q += 128){
      sattr[q >> 3][q & 7] = csr_ea8[(size_t)base*8 + q];
    }
    __syncthreads();
    for (int j = 0; j < cnt; ++j){
      float hv = bf2f(hin_bf[(size_t)ssrc[j]*128 + d]);
      float e = bd;
      #pragma unroll
      for (int k = 0; k < 7; ++k) e += sattr[j][k]*w[k];
      float m = hv + e;
      acc += (m > 0.f) ? m : 0.f;
    }
  }
  float one = 1.f + eps[l];
  float z = one*bf2f(hin_bf[(size_t)node*128 + d]) + acc;
  zout[(size_t)node*128 + d] = f2bf(z);
}

// GEMM1: y1h[N,256](bf16) = z_bf16[N,128] @ W1 + b1, column sum/sumsq atomics (fp32)
__global__ __launch_bounds__(256) void gemm1_kernel(const unsigned short* __restrict__ A,
                                                    const unsigned short* __restrict__ BT, // [256][128]
                                                    const float* __restrict__ bias,
                                                    unsigned short* __restrict__ Y,
                                                    float* __restrict__ sums, float* __restrict__ sqs){
  __shared__ __align__(16) unsigned short Al[128*128];
  __shared__ __align__(16) unsigned short Bl[128*128];
  const int t = threadIdx.x;
  const int rb = blockIdx.x, cb = blockIdx.y;
  for (int it = 0; it < 8; ++it){
    int idx = it*256 + t;
    int row = idx >> 4, ch = idx & 15;
    int grow = rb*128 + row;
    u32x4v v = {0,0,0,0};
    if (grow < NN) v = *(const u32x4v*)(A + (size_t)grow*128 + ch*8);
    *(u32x4v*)((char*)Al + row*256 + ((ch*16) ^ ((row&7)<<4))) = v;
  }
  for (int it = 0; it < 8; ++it){
    int idx = it*256 + t;
    int row = idx >> 4, ch = idx & 15;
    u32x4v v = *(const u32x4v*)(BT + (size_t)(cb*128 + row)*128 + ch*8);
    *(u32x4v*)((char*)Bl + row*256 + ((ch*16) ^ ((row&7)<<4))) = v;
  }
  __syncthreads();
  const int lane = t & 63, wave = t >> 6;
  const int wm = wave >> 1, wn = wave & 1;
  const int r0 = lane & 15, kg = lane >> 4;
  f32x4v acc[4][4] = {};
  #pragma unroll
  for (int kk = 0; kk < 4; ++kk){
    const int kb = kk*64 + kg*16;
    bf16x8 a[4], b[4];
    #pragma unroll
    for (int m = 0; m < 4; ++m){
      int row = wm*64 + m*16 + r0;
      a[m] = *(const bf16x8*)((const char*)Al + row*256 + (kb ^ ((r0&7)<<4)));
    }
    #pragma unroll
    for (int n = 0; n < 4; ++n){
      int col = wn*64 + n*16 + r0;
      b[n] = *(const bf16x8*)((const char*)Bl + col*256 + (kb ^ ((r0&7)<<4)));
    }
    #pragma unroll
    for (int m = 0; m < 4; ++m)
      #pragma unroll
      for (int n = 0; n < 4; ++n)
        acc[m][n] = __builtin_amdgcn_mfma_f32_16x16x32_bf16(a[m], b[n], acc[m][n], 0, 0, 0);
  }
  #pragma unroll
  for (int n = 0; n < 4; ++n){
    const int col = cb*128 + wn*64 + n*16 + r0;
    const float bv = bias[col];
    float s = 0.f, q = 0.f;
    #pragma unroll
    for (int m = 0; m < 4; ++m){
      const int rowb = rb*128 + wm*64 + m*16 + kg*4;
      #pragma unroll
      for (int j = 0; j < 4; ++j){
        int grow = rowb + j;
        if (grow < NN){
          float v = acc[m][n][j] + bv;
          Y[(size_t)grow*256 + col] = f2bf(v);
          s += v; q += v*v;
        }
      }
    }
    s += __shfl_xor(s, 16); q += __shfl_xor(q, 16);
    s += __shfl_xor(s, 32); q += __shfl_xor(q, 32);
    if (kg == 0){ atomicAdd(&sums[col], s); atomicAdd(&sqs[col], q); }
  }
}

// GEMM2: y2 = bnrelu(y1h)[N,256] @ W2 + b2; folds BN1 finalize in prologue; column stats.
// FINAL=0: write bf16 to Yh ; FINAL=1: write fp32 to Yf (d_out)
template<int FINAL>
__global__ __launch_bounds__(256) void gemm2_kernel(const unsigned short* __restrict__ Yin,
                                                    const float* __restrict__ sum1, const float* __restrict__ sq1,
                                                    const float* __restrict__ bg, const float* __restrict__ bb,
                                                    const unsigned short* __restrict__ BT, // [128][256]
                                                    const float* __restrict__ bias,
                                                    unsigned short* __restrict__ Yh, float* __restrict__ Yf,
                                                    float* __restrict__ sums, float* __restrict__ sqs){
  __shared__ __align__(16) unsigned short Al[128*128];
  __shared__ __align__(16) unsigned short Bl[128*128];
  __shared__ float s_scl[256], s_shf[256];
  const int t = threadIdx.x;
  const int rb = blockIdx.x;
  {
    const float invn = 1.f/(float)NN;
    float m = sum1[t]*invn;
    float var = sq1[t]*invn - m*m;
    var = var > 0.f ? var : 0.f;
    float sc = bg[t]*rsqrtf(var + 1e-5f);
    s_scl[t] = sc;
    s_shf[t] = bb[t] - m*sc;
  }
  const int lane = t & 63, wave = t >> 6;
  const int wm = wave >> 1, wn = wave & 1;
  const int r0 = lane & 15, kg = lane >> 4;
  f32x4v acc[4][4] = {};
  for (int kt = 0; kt < 2; ++kt){
    __syncthreads();   // kt=0: guards s_scl; kt=1: guards LDS reuse
    for (int it = 0; it < 8; ++it){
      int idx = it*256 + t;
      int row = idx >> 4, ch = idx & 15;
      int grow = rb*128 + row;
      int c0 = kt*128 + ch*8;
      u32x4v pv = {0,0,0,0};
      if (grow < NN){
        u32x4v yv = *(const u32x4v*)(Yin + (size_t)grow*256 + c0);
        unsigned short tb[8];
        #pragma unroll
        for (int jj = 0; jj < 4; ++jj){
          uint32_t pw = yv[jj];
          float a0 = bf2f((unsigned short)(pw & 0xFFFFu));
          float a1 = bf2f((unsigned short)(pw >> 16));
          float v0 = a0*s_scl[c0 + 2*jj]     + s_shf[c0 + 2*jj];
          float v1 = a1*s_scl[c0 + 2*jj + 1] + s_shf[c0 + 2*jj + 1];
          tb[2*jj]     = f2bf(v0 > 0.f ? v0 : 0.f);
          tb[2*jj + 1] = f2bf(v1 > 0.f ? v1 : 0.f);
        }
        pv[0] = (uint32_t)tb[0] | ((uint32_t)tb[1] << 16);
        pv[1] = (uint32_t)tb[2] | ((uint32_t)tb[3] << 16);
        pv[2] = (uint32_t)tb[4] | ((uint32_t)tb[5] << 16);
        pv[3] = (uint32_t)tb[6] | ((uint32_t)tb[7] << 16);
      }
      *(u32x4v*)((char*)Al + row*256 + ((ch*16) ^ ((row&7)<<4))) = pv;
    }
    for (int it = 0; it < 8; ++it){
      int idx = it*256 + t;
      int row = idx >> 4, ch = idx & 15;
      u32x4v v = *(const u32x4v*)(BT + (size_t)row*256 + kt*128 + ch*8);
      *(u32x4v*)((char*)Bl + row*256 + ((ch*16) ^ ((row&7)<<4))) = v;
    }
    __syncthreads();
    #pragma unroll
    for (int kk = 0; kk < 4; ++kk){
      const int kb = kk*64 + kg*16;
      bf16x8 a[4], b[4];
      #pragma unroll
      for (int m = 0; m < 4; ++m){
        int row = wm*64 + m*16 + r0;
        a[m] = *(const bf16x8*)((const char*)Al + row*256 + (kb ^ ((r0&7)<<4)));
      }
      #pragma unroll
      for (int n = 0; n < 4; ++n){
        int col = wn*64 + n*16 + r0;
        b[n] = *(const bf16x8*)((const char*)Bl + col*256 + (kb ^ ((r0&7)<<4)));
      }
      #pragma unroll
      for (int m = 0; m < 4; ++m)
        #pragma unroll
        for (int n = 0; n < 4; ++n)
          acc[m][n] = __builtin_amdgcn_mfma_f32_16x16x32_bf16(a[m], b[n], acc[m][n], 0, 0, 0);
    }
  }
  #pragma unroll
  for (int n = 0; n < 4; ++n){
    const int col = wn*64 + n*16 + r0;
    const float bv = bias[col];
    float s = 0.f, q = 0.f;
    #pragma unroll
    for (int m = 0; m < 4; ++m){
      const int rowb = rb*128 + wm*64 + m*16 + kg*4;
      #pragma unroll
      for (int j = 0; j < 4; ++j){
        int grow = rowb + j;
        if (grow < NN){
          float v = acc[m][n][j] + bv;
          if (FINAL) Yf[(size_t)grow*128 + col] = v;
          else       Yh[(size_t)grow*128 + col] = f2bf(v);
          s += v; q += v*v;
        }
      }
    }
    s += __shfl_xor(s, 16); q += __shfl_xor(q, 16);
    s += __shfl_xor(s, 32); q += __shfl_xor(q, 32);
    if (kg == 0){ atomicAdd(&sums[col], s); atomicAdd(&sqs[col], q); }
  }
}

// happly_fused (l < L-1): read y2(bf16) + stats -> BN+relu -> +vn[batch] -> hin_bf ; pool atomics
__global__ __launch_bounds__(128) void happly_fused_kernel(const unsigned short* __restrict__ y2h,
                                                           const float* __restrict__ sum2, const float* __restrict__ sq2,
                                                           const float* __restrict__ bg, const float* __restrict__ bb,
                                                           const float* __restrict__ vn, const int* __restrict__ batch,
                                                           unsigned short* __restrict__ hin_bf, float* __restrict__ vbuf_next){
  int r0 = blockIdx.x*128;
  int r1 = r0 + 128; if (r1 > NN) r1 = NN;
  int d = threadIdx.x;
  const float invn = 1.f/(float)NN;
  float m = sum2[d]*invn;
  float var = sq2[d]*invn - m*m;
  var = var > 0.f ? var : 0.f;
  float sc = bg[d]*rsqrtf(var + 1e-5f);
  float sh = bb[d] - m*sc;
  __shared__ int sb[128];
  if (r0 + d < r1) sb[d] = batch[r0 + d];
  __syncthreads();
  int curg = sb[0];
  float vnv = vn[(size_t)curg*DD + d];
  float pacc = 0.f;
  for (int r = r0; r < r1; ++r){
    int g = sb[r - r0];
    if (g != curg){
      atomicAdd(&vbuf_next[(size_t)curg*DD + d], pacc);
      pacc = 0.f; curg = g;
      vnv = vn[(size_t)curg*DD + d];
    }
    float y = bf2f(y2h[(size_t)r*DD + d]);
    float v = y*sc + sh;
    v = v > 0.f ? v : 0.f;
    float hv = v + vnv;
    hin_bf[(size_t)r*DD + d] = f2bf(hv);
    pacc += hv;
  }
  atomicAdd(&vbuf_next[(size_t)curg*DD + d], pacc);
}

// final layer: BN in-place on d_out (fp32), no relu
__global__ __launch_bounds__(256) void happly_final_kernel(float* __restrict__ y,
                                                           const float* __restrict__ sum2, const float* __restrict__ sq2,
                                                           const float* __restrict__ bg, const float* __restrict__ bb){
  int idx = blockIdx.x*256 + threadIdx.x;
  if (idx >= NN*32) return;
  int c4 = idx & 31;
  const float invn = 1.f/(float)NN;
  f32x4v yv = *(const f32x4v*)(y + (size_t)idx*4);
  f32x4v o;
  #pragma unroll
  for (int j = 0; j < 4; ++j){
    int c = c4*4 + j;
    float m = sum2[c]*invn;
    float var = sq2[c]*invn - m*m;
    var = var > 0.f ? var : 0.f;
    float sc = bg[c]*rsqrtf(var + 1e-5f);
    o[j] = (yv[j] - m)*sc + bb[c];
  }
  *(f32x4v*)(y + (size_t)idx*4) = o;
}

__global__ __launch_bounds__(256) void vmlp1_kernel(const float* __restrict__ vn, const float* __restrict__ vbufl,
                                                    const float* __restrict__ W, const float* __restrict__ bias,
                                                    float* __restrict__ Yo,
                                                    float* __restrict__ sums, float* __restrict__ sqs){
  __shared__ float vrow[128];
  int r = blockIdx.x, c = threadIdx.x;
  if (c < 128) vrow[c] = vn[r*128 + c] + vbufl[r*128 + c];
  __syncthreads();
  float acc = 0.f;
  #pragma unroll 8
  for (int k = 0; k < 128; ++k) acc += vrow[k]*W[k*256 + c];
  float y = acc + bias[c];
  Yo[r*256 + c] = y;
  atomicAdd(&sums[c], y);
  atomicAdd(&sqs[c], y*y);
}

__global__ __launch_bounds__(128) void vmlp2_kernel(const float* __restrict__ Yin,
                                                    const float* __restrict__ sumv1, const float* __restrict__ sqv1,
                                                    const float* __restrict__ vg, const float* __restrict__ vb,
                                                    const float* __restrict__ W, const float* __restrict__ bias,
                                                    float* __restrict__ Yo,
                                                    float* __restrict__ sums, float* __restrict__ sqs){
  __shared__ float arow[256];
  __shared__ float s_scl[256], s_shf[256];
  int r = blockIdx.x, c = threadIdx.x;
  const float invg = 1.f/(float)GG;
  for (int k = c; k < 256; k += 128){
    float m = sumv1[k]*invg;
    float var = sqv1[k]*invg - m*m;
    var = var > 0.f ? var : 0.f;
    float sc = vg[k]*rsqrtf(var + 1e-5f);
    s_scl[k] = sc;
    s_shf[k] = vb[k] - m*sc;
  }
  __syncthreads();
  for (int k = c; k < 256; k += 128){
    float a = Yin[r*256 + k]*s_scl[k] + s_shf[k];
    arow[k] = a > 0.f ? a : 0.f;
  }
  __syncthreads();
  float acc = 0.f;
  #pragma unroll 8
  for (int k = 0; k < 256; ++k) acc += arow[k]*W[k*128 + c];
  float y = acc + bias[c];
  Yo[r*128 + c] = y;
  atomicAdd(&sums[c], y);
  atomicAdd(&sqs[c], y*y);
}

__global__ __launch_bounds__(256) void va_kernel(const float* __restrict__ yv2,
                                                 const float* __restrict__ sumv2, const float* __restrict__ sqv2,
                                                 const float* __restrict__ vg, const float* __restrict__ vb,
                                                 float* __restrict__ vn){
  int idx = blockIdx.x*256 + threadIdx.x;
  if (idx < GG*128){
    int c = idx & 127;
    const float invg = 1.f/(float)GG;
    float m = sumv2[c]*invg;
    float var = sqv2[c]*invg - m*m;
    var = var > 0.f ? var : 0.f;
    float sc = vg[c]*rsqrtf(var + 1e-5f);
    float v = (yv2[idx] - m)*sc + vb[c];
    vn[idx] = v > 0.f ? v : 0.f;
  }
}

// ---------------- launch ----------------

extern "C" void kernel_launch(void* const* d_in, const int* in_sizes, int n_in,
                              void* d_out, int out_size, void* d_ws, size_t ws_size,
                              hipStream_t stream){
  const int*   x         = (const int*)  d_in[0];
  const int*   ei        = (const int*)  d_in[1];
  const float* edge_attr = (const float*)d_in[2];
  const int*   batch     = (const int*)  d_in[3];
  const float* node_emb  = (const float*)d_in[4];
  const float* vn_emb    = (const float*)d_in[5];
  const float* eps       = (const float*)d_in[6];
  const float* edge_W    = (const float*)d_in[7];
  const float* edge_b    = (const float*)d_in[8];
  const float* W1        = (const float*)d_in[9];
  const float* b1        = (const float*)d_in[10];
  const float* bn1_g     = (const float*)d_in[11];
  const float* bn1_b     = (const float*)d_in[12];
  const float* W2        = (const float*)d_in[13];
  const float* b2        = (const float*)d_in[14];
  const float* bn_g      = (const float*)d_in[15];
  const float* bn_b      = (const float*)d_in[16];
  const float* vn_W1     = (const float*)d_in[17];
  const float* vn_b1     = (const float*)d_in[18];
  const float* vn_bn1_g  = (const float*)d_in[19];
  const float* vn_bn1_b  = (const float*)d_in[20];
  const float* vn_W2     = (const float*)d_in[21];
  const float* vn_b2     = (const float*)d_in[22];
  const float* vn_bn2_g  = (const float*)d_in[23];
  const float* vn_bn2_b  = (const float*)d_in[24];
  float* hout = (float*)d_out;

  char* ws = (char*)d_ws;
  size_t off = 0;
  auto alloc = [&](size_t bytes)->char*{
    char* p = ws + off; off += (bytes + 255) & ~(size_t)255; return p;
  };
  unsigned short* hin_bf = (unsigned short*)alloc((size_t)NN*DD*2);
  unsigned short* zy     = (unsigned short*)alloc((size_t)NN*DD*2);   // zbuf / y2h (disjoint lifetimes)
  unsigned short* y1h    = (unsigned short*)alloc((size_t)NN*D2*2);
  float*          vn     = (float*)         alloc((size_t)GG*DD*4);
  float*          yv1    = (float*)         alloc((size_t)GG*D2*4);
  float*          yv2    = (float*)         alloc((size_t)GG*DD*4);
  unsigned short* W1T    = (unsigned short*)alloc((size_t)LL*D2*DD*2);
  unsigned short* W2T    = (unsigned short*)alloc((size_t)LL*D2*DD*2);
  // zero region: stats_all [LL][8][256] | vbuf_all [5][GG*DD] | counts [NN]
  const int STATS_F = LL*8*256;          // 10240
  const int VBUF_F  = 5*GG*DD;           // 81920
  const int ZTOT    = STATS_F + VBUF_F + NN;
  float* zeroreg = (float*)alloc((size_t)ZTOT*4);
  float* stats_all = zeroreg;
  float* vbuf_all  = zeroreg + STATS_F;
  int*   counts    = (int*)(zeroreg + STATS_F + VBUF_F);
  int*   startp = (int*)  alloc((size_t)(NN+1)*4);
  int*   cursor = (int*)  alloc((size_t)NN*4);
  int*   csr    = (int*)  alloc((size_t)EE*4);
  int*   bsums  = (int*)  alloc(128*4);
  int*   csr_src= (int*)  alloc((size_t)EE*4);
  float* csr_ea8= (float*)alloc((size_t)EE*8*4);

  const int nb_scan = (NN + SCAN_B - 1)/SCAN_B;   // 98
  const int row_blocks = (NN + 127)/128;           // 391
  const int ew_blocks = (NN*32 + 255)/256;         // 6250

  // ---- setup ----
  zero_kernel<<<(ZTOT + 255)/256, 256, 0, stream>>>(zeroreg, ZTOT);
  count_kernel<<<EE/256, 256, 0, stream>>>(ei, counts);
  scan1_kernel<<<nb_scan, SCAN_B, 0, stream>>>(counts, bsums, NN);
  scan2_kernel<<<1, 64, 0, stream>>>(bsums, nb_scan);
  scan3_kernel<<<nb_scan, SCAN_B, 0, stream>>>(counts, bsums, startp, cursor, NN);
  fill_kernel<<<EE/256, 256, 0, stream>>>(ei, cursor, csr);
  egather_kernel<<<EE/256, 256, 0, stream>>>(csr, ei, edge_attr, csr_src, csr_ea8);
  wtrans_kernel<<<(2*LL*DD*D2 + 255)/256, 256, 0, stream>>>(W1, W2, W1T, W2T);
  init_kernel<<<row_blocks, 128, 0, stream>>>(x, batch, node_emb, vn_emb, hin_bf, vbuf_all, vn);

  for (int l = 0; l < LL; ++l){
    float* st    = stats_all + (size_t)l*8*256;
    float* sum1  = st + 0*256, *sq1  = st + 1*256;
    float* sum2  = st + 2*256, *sq2  = st + 3*256;
    float* sumv1 = st + 4*256, *sqv1 = st + 5*256;
    float* sumv2 = st + 6*256, *sqv2 = st + 7*256;

    agg2_kernel<<<NN, 128, 0, stream>>>(hin_bf, csr_src, csr_ea8, startp,
                                        edge_W + (size_t)l*7*DD, edge_b + (size_t)l*DD, eps, l, zy);
    gemm1_kernel<<<dim3(row_blocks, 2), 256, 0, stream>>>(zy, W1T + (size_t)l*32768,
                                                          b1 + (size_t)l*D2, y1h, sum1, sq1);
    if (l != LL-1){
      gemm2_kernel<0><<<row_blocks, 256, 0, stream>>>(y1h, sum1, sq1,
                                                      bn1_g + (size_t)l*D2, bn1_b + (size_t)l*D2,
                                                      W2T + (size_t)l*32768, b2 + (size_t)l*DD,
                                                      zy, nullptr, sum2, sq2);
      float* vbufl = vbuf_all + (size_t)l*GG*DD;
      float* vbufn = vbuf_all + (size_t)(l+1)*GG*DD;
      vmlp1_kernel<<<GG, 256, 0, stream>>>(vn, vbufl, vn_W1 + (size_t)l*DD*D2, vn_b1 + (size_t)l*D2,
                                           yv1, sumv1, sqv1);
      vmlp2_kernel<<<GG, 128, 0, stream>>>(yv1, sumv1, sqv1,
                                           vn_bn1_g + (size_t)l*D2, vn_bn1_b + (size_t)l*D2,
                                           vn_W2 + (size_t)l*D2*DD, vn_b2 + (size_t)l*DD,
                                           yv2, sumv2, sqv2);
      va_kernel<<<(GG*DD + 255)/256, 256, 0, stream>>>(yv2, sumv2, sqv2,
                                                       vn_bn2_g + (size_t)l*DD, vn_bn2_b + (size_t)l*DD, vn);
      happly_fused_kernel<<<row_blocks, 128, 0, stream>>>(zy, sum2, sq2,
                                                          bn_g + (size_t)l*DD, bn_b + (size_t)l*DD,
                                                          vn, batch, hin_bf, vbufn);
    } else {
      gemm2_kernel<1><<<row_blocks, 256, 0, stream>>>(y1h, sum1, sq1,
                                                      bn1_g + (size_t)l*D2, bn1_b + (size_t)l*D2,
                                                      W2T + (size_t)l*32768, b2 + (size_t)l*DD,
                                                      nullptr, hout, sum2, sq2);
      happly_final_kernel<<<ew_blocks, 256, 0, stream>>>(hout, sum2, sq2,
                                                         bn_g + (size_t)l*DD, bn_b + (size_t)l*DD);
    }
  }
  (void)in_sizes; (void)n_in; (void)out_size; (void)ws_size;
}